// Round 11
// baseline (55.918 us; speedup 1.0000x reference)
//
#include <hip/hip_runtime.h>

// SeesawLoss forward, N=32768 rows, C=1203 classes (+2 binary logits).
// Round 11 = round-8 structure + 2-row ILP in the row kernel:
// each wave computes TWO grid-stride rows (n, n+nw) concurrently --
// independent load streams and interleaved shuffle-tree chains double the
// per-wave MLP/ILP, compensating the 4-waves/SIMD occupancy of the 65-128
// VGPR band (m69: occupancy halves at the 64-VGPR step). The x4-replicated
// P*log2(cum) table returns (20480 B LDS, conflict-free ds_read_b128, and
// each 16B read is SHARED by both rows). __launch_bounds__(256,4) caps at
// 128 VGPR with ~40 VGPR margin over the ~85-VGPR state (round 6's spill
// came from a 64-cap against 90+ state; tripwire = warm WRITE_SIZE).
// 3 dispatches: prep (1-block hist + replicated table), row, reduce.
// No float atomics, no ordered atomics.

#define C_CLS   1203
#define ROW_LEN 1205
#define NBINS   1204
#define RPAD    1280
#define NEG_HUGE (-3.402823466e38f)
#define LOG2E    1.4426950408889634f
#define LN2      0.6931471805599453f
#define LOG_EPS2 (-6.643856189774724f)   // log2(0.01)
#define P_POW    0.8f
#define Q_POW    2.0f
#define M2FIX    16.0f                   // fixed softmax shift (|logits| << 11)

#if __has_builtin(__builtin_amdgcn_exp2f)
#define EXP2(x) __builtin_amdgcn_exp2f(x)
#else
#define EXP2(x) exp2f(x)
#endif
#if __has_builtin(__builtin_amdgcn_logf)
#define LOG2F_(x) __builtin_amdgcn_logf(x)
#else
#define LOG2F_(x) __log2f(x)
#endif

// ---------------- dispatch 1: histogram + replicated P*log2(count) table ----
__launch_bounds__(1024)
__global__ void prep_k(const int* __restrict__ labels, int N,
                       float* __restrict__ plgG) {
    __shared__ unsigned hist[NBINS];
    for (int i = threadIdx.x; i < NBINS; i += 1024) hist[i] = 0u;
    __syncthreads();

    const int nv = N >> 2;
    const int4* lp = (const int4*)labels;
    for (int i = threadIdx.x; i < nv; i += 1024) {
        int4 v = lp[i];
        atomicAdd(&hist[v.x], 1u); atomicAdd(&hist[v.y], 1u);
        atomicAdd(&hist[v.z], 1u); atomicAdd(&hist[v.w], 1u);
    }
    for (int i = (N & ~3) + (int)threadIdx.x; i < N; i += 1024)
        atomicAdd(&hist[labels[i]], 1u);
    __syncthreads();

    for (int u = threadIdx.x; u < RPAD; u += 1024) {
        #pragma unroll
        for (int kk = 0; kk < 4; ++kk) {
            int j = u + kk;
            float v = 0.0f;
            if (j < NBINS) v = P_POW * LOG2F_(fmaxf((float)hist[j], 1.0f));
            plgG[kk * RPAD + u] = v;
        }
    }
}

// Row loader: 5 float4 segments (segs 0-3 pure classes, seg 4 masked) +
// prefix + wave-uniform labv/c0/c1.
#define LOADV(row_, label_, q_, pv_, labv_, c0_, c1_, k_) do {                  \
    labv_ = row_[label_]; c0_ = row_[C_CLS]; c1_ = row_[C_CLS + 1];             \
    const float4* vp_ = (const float4*)(row_ + (k_));                           \
    _Pragma("unroll")                                                           \
    for (int i_ = 0; i_ < 4; ++i_) q_[i_] = vp_[(size_t)i_ * 64 + lane];        \
    {   int b4_ = (k_) + 1024 + 4 * lane;                                       \
        float4 t_ = make_float4(NEG_HUGE, NEG_HUGE, NEG_HUGE, NEG_HUGE);        \
        if (b4_ + 3 <= C_CLS - 1) { t_ = vp_[(size_t)256 + lane]; }             \
        else { if (b4_     <= C_CLS - 1) t_.x = row_[b4_];                      \
               if (b4_ + 1 <= C_CLS - 1) t_.y = row_[b4_ + 1];                  \
               if (b4_ + 2 <= C_CLS - 1) t_.z = row_[b4_ + 2]; }                \
        q_[4] = t_; }                                                           \
    pv_ = (lane < (k_)) ? row_[lane] : NEG_HUGE;                                \
} while (0)

// ---------------- dispatch 2: per-row loss, TWO rows per wave in flight ----
__launch_bounds__(256, 4)   // cap 128 VGPR; state ~85 -> no spill expected
__global__ void seesaw_row_k(const float* __restrict__ cls,
                             const int* __restrict__ labels,
                             const float* __restrict__ lweights,
                             const float* __restrict__ plgG,
                             float* __restrict__ wsums,
                             int N) {
    __shared__ __align__(16) float plg[4][RPAD];   // 20480 B
    {
        const float4* src = (const float4*)plgG;
        float4* dst = (float4*)&plg[0][0];
        for (int i = threadIdx.x; i < RPAD; i += 256) dst[i] = src[i];
    }
    __syncthreads();

    const int lane = threadIdx.x & 63;
    const int wv   = threadIdx.x >> 6;
    const int wid  = blockIdx.x * 4 + wv;
    const int nw   = gridDim.x * 4;        // multiple of 4 -> k wave-invariant

    float acc = 0.0f;

    for (int n = wid; n < N; n += 2 * nw) {
        const int  nB    = n + nw;
        const bool haveB = (nB < N);
        const int k = (-n) & 3;            // same for nB (nw % 4 == 0)

        const float* rowA = cls + (size_t)n * ROW_LEN;
        const float* rowB = cls + (size_t)(haveB ? nB : n) * ROW_LEN;
        const int   labA  = labels[n];
        const float wA    = lweights[n];
        const int   labB  = haveB ? labels[nB] : 0;
        const float wB    = haveB ? lweights[nB] : 0.0f;

        // ---- load both rows (independent streams, MLP x2) ----
        float4 qA[5], qB[5];
        float pvA, labvA, c0A, c1A, pvB, labvB, c0B, c1B;
        LOADV(rowA, labA, qA, pvA, labvA, c0A, c1A, k);
        LOADV(rowB, labB, qB, pvB, labvB, c0B, c1B, k);

        // ---- pass 1 (both rows): log2 domain, s = sum 2^(xl - 16) ----
        pvA *= LOG2E; pvB *= LOG2E;
        float sA = EXP2(pvA - M2FIX);
        float sB = EXP2(pvB - M2FIX);
        #pragma unroll
        for (int i = 0; i < 5; ++i) {
            qA[i].x *= LOG2E; qA[i].y *= LOG2E; qA[i].z *= LOG2E; qA[i].w *= LOG2E;
            sA += EXP2(qA[i].x - M2FIX) + EXP2(qA[i].y - M2FIX)
                + EXP2(qA[i].z - M2FIX) + EXP2(qA[i].w - M2FIX);
            qB[i].x *= LOG2E; qB[i].y *= LOG2E; qB[i].z *= LOG2E; qB[i].w *= LOG2E;
            sB += EXP2(qB[i].x - M2FIX) + EXP2(qB[i].y - M2FIX)
                + EXP2(qB[i].z - M2FIX) + EXP2(qB[i].w - M2FIX);
        }
        #pragma unroll
        for (int o = 32; o > 0; o >>= 1) {        // two independent chains
            sA += __shfl_xor(sA, o, 64);
            sB += __shfl_xor(sB, o, 64);
        }

        const float L2A = M2FIX + LOG2F_(sA);
        const float L2B = M2FIX + LOG2F_(sB);
        const float lvA = labvA * LOG2E,            lvB = labvB * LOG2E;
        const float GA  = fmaxf(lvA, L2A + LOG_EPS2), GB = fmaxf(lvB, L2B + LOG_EPS2);
        const float WA  = L2A + Q_POW * (L2A - GA),   WB = L2B + Q_POW * (L2B - GB);
        const float WpA = WA + plg[0][labA],          WpB = WB + plg[0][labB];
        const float mWA = -WA,                        mWB = -WB;

        // ---- pass 2 (both rows, SHARED table read) ----
        float TA, TB;
        {
            const float lgpv = plg[0][lane];
            float tA = fminf(lgpv - WpA, mWA), hA = fmaxf(pvA - GA, 0.0f);
            TA = EXP2(fmaf(Q_POW, hA, pvA) + tA);
            float tB = fminf(lgpv - WpB, mWB), hB = fmaxf(pvB - GB, 0.0f);
            TB = EXP2(fmaf(Q_POW, hB, pvB) + tB);
        }
        #pragma unroll
        for (int i = 0; i < 5; ++i) {
            const float4 lg = *(const float4*)&plg[k][256 * i + 4 * lane];
            { float t = fminf(lg.x - WpA, mWA), h = fmaxf(qA[i].x - GA, 0.f);
              TA += EXP2(fmaf(Q_POW, h, qA[i].x) + t); }
            { float t = fminf(lg.x - WpB, mWB), h = fmaxf(qB[i].x - GB, 0.f);
              TB += EXP2(fmaf(Q_POW, h, qB[i].x) + t); }
            { float t = fminf(lg.y - WpA, mWA), h = fmaxf(qA[i].y - GA, 0.f);
              TA += EXP2(fmaf(Q_POW, h, qA[i].y) + t); }
            { float t = fminf(lg.y - WpB, mWB), h = fmaxf(qB[i].y - GB, 0.f);
              TB += EXP2(fmaf(Q_POW, h, qB[i].y) + t); }
            { float t = fminf(lg.z - WpA, mWA), h = fmaxf(qA[i].z - GA, 0.f);
              TA += EXP2(fmaf(Q_POW, h, qA[i].z) + t); }
            { float t = fminf(lg.z - WpB, mWB), h = fmaxf(qB[i].z - GB, 0.f);
              TB += EXP2(fmaf(Q_POW, h, qB[i].z) + t); }
            { float t = fminf(lg.w - WpA, mWA), h = fmaxf(qA[i].w - GA, 0.f);
              TA += EXP2(fmaf(Q_POW, h, qA[i].w) + t); }
            { float t = fminf(lg.w - WpB, mWB), h = fmaxf(qB[i].w - GB, 0.f);
              TB += EXP2(fmaf(Q_POW, h, qB[i].w) + t); }
        }
        #pragma unroll
        for (int o = 32; o > 0; o >>= 1) {        // two independent chains
            TA += __shfl_xor(TA, o, 64);
            TB += __shfl_xor(TB, o, 64);
        }
        TA -= EXP2(lvA - WA);  TA = fmaxf(TA, 1e-37f);
        TB -= EXP2(lvB - WB);  TB = fmaxf(TB, 1e-37f);

        // ---- per-row tails (wave-uniform) ----
        {
            const float nl2 = WA + LOG2F_(TA);
            const float xx  = (nl2 - lvA) * LN2;
            const float rl  = (xx > 0.0f) ? (xx + log1pf(__expf(-xx)))
                                          : log1pf(__expf(xx));
            const float mm   = fmaxf(c0A, c1A);
            const float lseb = mm + __logf(__expf(c0A - mm) + __expf(c1A - mm));
            const float ce   = lseb - ((labA == C_CLS) ? c1A : c0A);
            acc += ((wA == 1.0f) ? rl : 0.0f) + ce * wA;
        }
        if (haveB) {
            const float nl2 = WB + LOG2F_(TB);
            const float xx  = (nl2 - lvB) * LN2;
            const float rl  = (xx > 0.0f) ? (xx + log1pf(__expf(-xx)))
                                          : log1pf(__expf(xx));
            const float mm   = fmaxf(c0B, c1B);
            const float lseb = mm + __logf(__expf(c0B - mm) + __expf(c1B - mm));
            const float ce   = lseb - ((labB == C_CLS) ? c1B : c0B);
            acc += ((wB == 1.0f) ? rl : 0.0f) + ce * wB;
        }
    }

    if (lane == 0) wsums[wid] = acc;   // per-wave partial, plain store
}

// ---------------- dispatch 3: deterministic final sum ----------------
__launch_bounds__(512)
__global__ void reduce_k(const float* __restrict__ wsums, int nb,
                         const int* __restrict__ avg_raw,
                         float* __restrict__ out) {
    int tid = threadIdx.x;
    float s = 0.0f;
    int nb4 = nb >> 2;
    const float4* bp = (const float4*)wsums;
    for (int i = tid; i < nb4; i += 512) {
        float4 v = bp[i];
        s += (v.x + v.y) + (v.z + v.w);
    }
    for (int i = (nb4 << 2) + tid; i < nb; i += 512) s += wsums[i];

    #pragma unroll
    for (int o = 32; o > 0; o >>= 1) s += __shfl_xor(s, o, 64);

    __shared__ float ws8[8];
    int lane = tid & 63, wvi = tid >> 6;
    if (lane == 0) ws8[wvi] = s;
    __syncthreads();
    if (tid == 0) {
        float t = 0.0f;
        #pragma unroll
        for (int i = 0; i < 8; ++i) t += ws8[i];
        int ai = avg_raw[0];
        float af;
        if (ai > 0 && ai < (1 << 26)) {
            af = (float)ai;              // stored as integer
        } else {
            union { int i; float f; } u; // stored as float bits
            u.i = ai;
            af = u.f;
        }
        out[0] = t / af;
    }
}

extern "C" void kernel_launch(void* const* d_in, const int* in_sizes, int n_in,
                              void* d_out, int out_size, void* d_ws, size_t ws_size,
                              hipStream_t stream) {
    const float* cls    = (const float*)d_in[0];
    const int*   labels = (const int*)d_in[1];
    const float* lw     = (const float*)d_in[2];
    const int*   avgp   = (const int*)d_in[3];
    float*       out    = (float*)d_out;

    const int N = in_sizes[1];

    // ws layout: [ float plgG[4*RPAD] | float wsums[g*4] ]
    float* plgG  = (float*)d_ws;
    float* wsums = (float*)d_ws + 4 * RPAD;

    int g = (N + 15) / 16;               // 4 waves/block * 4 rows/wave
    if (g > 2048) g = 2048;
    if (g < 1) g = 1;

    prep_k<<<1, 1024, 0, stream>>>(labels, N, plgG);
    seesaw_row_k<<<g, 256, 0, stream>>>(cls, labels, lw, plgG, wsums, N);
    reduce_k<<<1, 512, 0, stream>>>(wsums, g * 4, avgp, out);
}

// Round 12
// 52.176 us; speedup vs baseline: 1.0717x; 1.0717x over previous
//
#include <hip/hip_runtime.h>

// SeesawLoss forward, N=32768 rows, C=1203 classes (+2 binary logits).
// Round 12 = round-10 base (best measured, 48.3: register-hoisted table,
// 5 KB LDS, uncapped VGPR) + OVERLAPPED next-row prefetch:
// issue row n+nw's global loads, THEN compute row n -- keeps the memory
// pipe busy during the ~600-cycle compute phase (R11's failed variant
// batched 2 rows serially, which leaves the same memory-idle gap).
// Critically: NO __launch_bounds__ min-waves/VGPR cap. R6 ran this exact
// prefetch under a 64-VGPR cap and spilled 264 MB/dispatch; R8 proved
// uncapped allocation of this body doesn't spill. Expected state ~95 VGPR
// -> 4 waves/SIMD (65-128 band), same occupancy as R10 but ~2x memory
// duty cycle. Spill tripwire: warm WRITE_SIZE >> 32 KB.
// 3 dispatches: prep (1-block hist + 5KB table), row, reduce.
// No float atomics, no ordered atomics.

#define C_CLS   1203
#define ROW_LEN 1205
#define NBINS   1204
#define RPAD    1280
#define NEG_HUGE (-3.402823466e38f)
#define LOG2E    1.4426950408889634f
#define LN2      0.6931471805599453f
#define LOG_EPS2 (-6.643856189774724f)   // log2(0.01)
#define P_POW    0.8f
#define Q_POW    2.0f
#define M2FIX    16.0f                   // fixed softmax shift (|logits| << 11)

#if __has_builtin(__builtin_amdgcn_exp2f)
#define EXP2(x) __builtin_amdgcn_exp2f(x)
#else
#define EXP2(x) exp2f(x)
#endif
#if __has_builtin(__builtin_amdgcn_logf)
#define LOG2F_(x) __builtin_amdgcn_logf(x)
#else
#define LOG2F_(x) __log2f(x)
#endif

// ---------------- dispatch 1: histogram + single-copy P*log2(count) table ----
__launch_bounds__(1024)
__global__ void prep_k(const int* __restrict__ labels, int N,
                       float* __restrict__ plgG) {
    __shared__ unsigned hist[NBINS];
    for (int i = threadIdx.x; i < NBINS; i += 1024) hist[i] = 0u;
    __syncthreads();

    const int nv = N >> 2;
    const int4* lp = (const int4*)labels;
    for (int i = threadIdx.x; i < nv; i += 1024) {
        int4 v = lp[i];
        atomicAdd(&hist[v.x], 1u); atomicAdd(&hist[v.y], 1u);
        atomicAdd(&hist[v.z], 1u); atomicAdd(&hist[v.w], 1u);
    }
    for (int i = (N & ~3) + (int)threadIdx.x; i < N; i += 1024)
        atomicAdd(&hist[labels[i]], 1u);
    __syncthreads();

    for (int u = threadIdx.x; u < RPAD; u += 1024) {
        float v = 0.0f;
        if (u < NBINS) v = P_POW * LOG2F_(fmaxf((float)hist[u], 1.0f));
        plgG[u] = v;     // pad region = 0 (masked elements are -inf in q)
    }
}

// Row loader: 5 float4 segments (segs 0-3 pure classes, seg 4 masked) +
// prefix + wave-uniform labv/c0/c1.
#define LOADV(row_, label_, q_, pv_, labv_, c0_, c1_, k_) do {                  \
    labv_ = row_[label_]; c0_ = row_[C_CLS]; c1_ = row_[C_CLS + 1];             \
    const float4* vp_ = (const float4*)(row_ + (k_));                           \
    _Pragma("unroll")                                                           \
    for (int i_ = 0; i_ < 4; ++i_) q_[i_] = vp_[(size_t)i_ * 64 + lane];        \
    {   int b4_ = (k_) + 1024 + 4 * lane;                                       \
        float4 t_ = make_float4(NEG_HUGE, NEG_HUGE, NEG_HUGE, NEG_HUGE);        \
        if (b4_ + 3 <= C_CLS - 1) { t_ = vp_[(size_t)256 + lane]; }             \
        else { if (b4_     <= C_CLS - 1) t_.x = row_[b4_];                      \
               if (b4_ + 1 <= C_CLS - 1) t_.y = row_[b4_ + 1];                  \
               if (b4_ + 2 <= C_CLS - 1) t_.z = row_[b4_ + 2]; }                \
        q_[4] = t_; }                                                           \
    pv_ = (lane < (k_)) ? row_[lane] : NEG_HUGE;                                \
} while (0)

// ---------------- dispatch 2: per-row loss, one wave per row, prefetched ----
__launch_bounds__(256)   // no min-waves clause: let VGPRs float, forbid spill
__global__ void seesaw_row_k(const float* __restrict__ cls,
                             const int* __restrict__ labels,
                             const float* __restrict__ lweights,
                             const float* __restrict__ plgG,
                             float* __restrict__ wsums,
                             int N) {
    __shared__ __align__(16) float plg[RPAD];   // 5120 B single copy
    {
        const float4* src = (const float4*)plgG;
        float4* dst = (float4*)plg;
        for (int i = threadIdx.x; i < RPAD / 4; i += 256) dst[i] = src[i];
    }
    __syncthreads();

    const int lane = threadIdx.x & 63;
    const int wv   = threadIdx.x >> 6;
    const int wid  = blockIdx.x * 4 + wv;
    const int nw   = gridDim.x * 4;        // multiple of 4 -> k wave-invariant

    float acc = 0.0f;
    int n = wid;
    if (n < N) {
        const int k = (-n) & 3;            // row base % 4 == n % 4 (1205%4==1)

        // ---- hoist the lane's 21 loop-invariant table values to registers
        const float lgp = plg[lane];       // prefix entry (lanes < k use it)
        float4 lgr[5];
        #pragma unroll
        for (int i = 0; i < 5; ++i) {
            const int u = k + 256 * i + 4 * lane;
            lgr[i].x = plg[u];     lgr[i].y = plg[u + 1];
            lgr[i].z = plg[u + 2]; lgr[i].w = plg[u + 3];
        }

        // ---- load first row's state ----
        int   labc = labels[n];
        float wc   = lweights[n];
        float plgl = plg[labc];
        float4 q[5]; float pv, labv, c0, c1;
        {
            const float* row = cls + (size_t)n * ROW_LEN;
            LOADV(row, labc, q, pv, labv, c0, c1, k);
        }

        for (;;) {
            // ---- prefetch next row: loads issue NOW, retire under compute
            const int  n2    = n + nw;
            const bool have2 = (n2 < N);
            float4 qn[5]; float pvn = 0.f, labvn = 0.f, c0n = 0.f, c1n = 0.f;
            int labn = 0; float wn = 0.0f, plgln = 0.0f;
            if (have2) {
                labn  = labels[n2];
                wn    = lweights[n2];
                plgln = plg[labn];
                const float* row2 = cls + (size_t)n2 * ROW_LEN;
                LOADV(row2, labn, qn, pvn, labvn, c0n, c1n, k);
            }

            // ---- pass 1: log2 domain in place, s = sum 2^(xl - 16)
            pv *= LOG2E;
            float s = EXP2(pv - M2FIX);
            #pragma unroll
            for (int i = 0; i < 5; ++i) {
                q[i].x *= LOG2E; q[i].y *= LOG2E;
                q[i].z *= LOG2E; q[i].w *= LOG2E;
                s += EXP2(q[i].x - M2FIX) + EXP2(q[i].y - M2FIX)
                   + EXP2(q[i].z - M2FIX) + EXP2(q[i].w - M2FIX);
            }
            #pragma unroll
            for (int o = 32; o > 0; o >>= 1) s += __shfl_xor(s, o, 64);

            const float L2    = M2FIX + LOG2F_(s);
            const float labv2 = labv * LOG2E;
            const float G     = fmaxf(labv2, L2 + LOG_EPS2);  // L2 + logsm2
            const float W     = L2 + Q_POW * (L2 - G);        // >= max adj
            const float Wp    = W + plgl;
            const float mW    = -W;

            // ---- pass 2: T = sum 2^(adj - W); label term subtracted after
            float T;
            {
                float t = fminf(lgp - Wp, mW);
                float h = fmaxf(pv - G, 0.0f);
                T = EXP2(fmaf(Q_POW, h, pv) + t);
            }
            #pragma unroll
            for (int i = 0; i < 5; ++i) {
                { float t = fminf(lgr[i].x - Wp, mW), h = fmaxf(q[i].x - G, 0.f);
                  T += EXP2(fmaf(Q_POW, h, q[i].x) + t); }
                { float t = fminf(lgr[i].y - Wp, mW), h = fmaxf(q[i].y - G, 0.f);
                  T += EXP2(fmaf(Q_POW, h, q[i].y) + t); }
                { float t = fminf(lgr[i].z - Wp, mW), h = fmaxf(q[i].z - G, 0.f);
                  T += EXP2(fmaf(Q_POW, h, q[i].z) + t); }
                { float t = fminf(lgr[i].w - Wp, mW), h = fmaxf(q[i].w - G, 0.f);
                  T += EXP2(fmaf(Q_POW, h, q[i].w) + t); }
            }
            #pragma unroll
            for (int o = 32; o > 0; o >>= 1) T += __shfl_xor(T, o, 64);
            T -= EXP2(labv2 - W);     // adj[label] == csc[label] exactly
            T = fmaxf(T, 1e-37f);

            // ---- per-row tail (wave-uniform)
            const float nl2 = W + LOG2F_(T);
            const float xx  = (nl2 - labv2) * LN2;
            const float rl  = (xx > 0.0f) ? (xx + log1pf(__expf(-xx)))
                                          : log1pf(__expf(xx));
            const float mm   = fmaxf(c0, c1);
            const float lseb = mm + __logf(__expf(c0 - mm) + __expf(c1 - mm));
            const float ce   = lseb - ((labc == C_CLS) ? c1 : c0);
            const float rlw  = (wc == 1.0f) ? rl : 0.0f;   // pos_mask == 1.0
            acc += rlw + ce * wc;

            if (!have2) break;
            n = n2; labc = labn; wc = wn; plgl = plgln;
            labv = labvn; c0 = c0n; c1 = c1n; pv = pvn;
            #pragma unroll
            for (int i = 0; i < 5; ++i) q[i] = qn[i];
        }
    }

    if (lane == 0) wsums[wid] = acc;   // per-wave partial, plain store
}

// ---------------- dispatch 3: deterministic final sum ----------------
__launch_bounds__(512)
__global__ void reduce_k(const float* __restrict__ wsums, int nb,
                         const int* __restrict__ avg_raw,
                         float* __restrict__ out) {
    int tid = threadIdx.x;
    float s = 0.0f;
    int nb4 = nb >> 2;
    const float4* bp = (const float4*)wsums;
    for (int i = tid; i < nb4; i += 512) {
        float4 v = bp[i];
        s += (v.x + v.y) + (v.z + v.w);
    }
    for (int i = (nb4 << 2) + tid; i < nb; i += 512) s += wsums[i];

    #pragma unroll
    for (int o = 32; o > 0; o >>= 1) s += __shfl_xor(s, o, 64);

    __shared__ float ws8[8];
    int lane = tid & 63, wvi = tid >> 6;
    if (lane == 0) ws8[wvi] = s;
    __syncthreads();
    if (tid == 0) {
        float t = 0.0f;
        #pragma unroll
        for (int i = 0; i < 8; ++i) t += ws8[i];
        int ai = avg_raw[0];
        float af;
        if (ai > 0 && ai < (1 << 26)) {
            af = (float)ai;              // stored as integer
        } else {
            union { int i; float f; } u; // stored as float bits
            u.i = ai;
            af = u.f;
        }
        out[0] = t / af;
    }
}

extern "C" void kernel_launch(void* const* d_in, const int* in_sizes, int n_in,
                              void* d_out, int out_size, void* d_ws, size_t ws_size,
                              hipStream_t stream) {
    const float* cls    = (const float*)d_in[0];
    const int*   labels = (const int*)d_in[1];
    const float* lw     = (const float*)d_in[2];
    const int*   avgp   = (const int*)d_in[3];
    float*       out    = (float*)d_out;

    const int N = in_sizes[1];

    // ws layout: [ float plgG[RPAD] | float wsums[g*4] ]
    float* plgG  = (float*)d_ws;
    float* wsums = (float*)d_ws + RPAD;

    int g = (N + 15) / 16;               // 4 waves/block * 4 rows/wave
    if (g > 2048) g = 2048;
    if (g < 1) g = 1;

    prep_k<<<1, 1024, 0, stream>>>(labels, N, plgG);
    seesaw_row_k<<<g, 256, 0, stream>>>(cls, labels, lw, plgG, wsums, N);
    reduce_k<<<1, 512, 0, stream>>>(wsums, g * 4, avgp, out);
}

// Round 13
// 49.745 us; speedup vs baseline: 1.1241x; 1.0489x over previous
//
#include <hip/hip_runtime.h>

// SeesawLoss forward, N=32768 rows, C=1203 classes (+2 binary logits).
// Round 13 = REVERT to round-10 (best measured, 48.3 us: register-hoisted
// table, 5 KB LDS, uncapped VGPR, scalar-only label/weight pipeline) with
// ONE delta: 2 rows/wave (g=4096 blocks) instead of 16 rows/wave (g=2048).
// Mechanism: more block boundaries -> more hardware-scheduler wave churn ->
// fresh waves' loads overlap retiring waves' compute at zero register cost.
// Ledger: occupancy-insensitive (R5 8w/SIMD 48.6 vs R10 4w/SIMD 48.3),
// prefetch-negative (R6/R11/R12), interior +-3 us -> kernel is bound by
// warm-L3 streaming (~4.2 TB/s effective) + ~9 us fixed overhead.
// 3 dispatches. No float atomics, no ordered atomics.

#define C_CLS   1203
#define ROW_LEN 1205
#define NBINS   1204
#define RPAD    1280
#define NEG_HUGE (-3.402823466e38f)
#define LOG2E    1.4426950408889634f
#define LN2      0.6931471805599453f
#define LOG_EPS2 (-6.643856189774724f)   // log2(0.01)
#define P_POW    0.8f
#define Q_POW    2.0f
#define M2FIX    16.0f                   // fixed softmax shift (|logits| << 11)

#if __has_builtin(__builtin_amdgcn_exp2f)
#define EXP2(x) __builtin_amdgcn_exp2f(x)
#else
#define EXP2(x) exp2f(x)
#endif
#if __has_builtin(__builtin_amdgcn_logf)
#define LOG2F_(x) __builtin_amdgcn_logf(x)
#else
#define LOG2F_(x) __log2f(x)
#endif

// ---------------- dispatch 1: histogram + single-copy P*log2(count) table ----
__launch_bounds__(1024)
__global__ void prep_k(const int* __restrict__ labels, int N,
                       float* __restrict__ plgG) {
    __shared__ unsigned hist[NBINS];
    for (int i = threadIdx.x; i < NBINS; i += 1024) hist[i] = 0u;
    __syncthreads();

    const int nv = N >> 2;
    const int4* lp = (const int4*)labels;
    for (int i = threadIdx.x; i < nv; i += 1024) {
        int4 v = lp[i];
        atomicAdd(&hist[v.x], 1u); atomicAdd(&hist[v.y], 1u);
        atomicAdd(&hist[v.z], 1u); atomicAdd(&hist[v.w], 1u);
    }
    for (int i = (N & ~3) + (int)threadIdx.x; i < N; i += 1024)
        atomicAdd(&hist[labels[i]], 1u);
    __syncthreads();

    for (int u = threadIdx.x; u < RPAD; u += 1024) {
        float v = 0.0f;
        if (u < NBINS) v = P_POW * LOG2F_(fmaxf((float)hist[u], 1.0f));
        plgG[u] = v;     // pad region = 0 (masked elements are -inf in q)
    }
}

// ---------------- dispatch 2: per-row loss, one wave per row ----------------
__launch_bounds__(256)   // no min-waves clause: let VGPRs float, forbid spill
__global__ void seesaw_row_k(const float* __restrict__ cls,
                             const int* __restrict__ labels,
                             const float* __restrict__ lweights,
                             const float* __restrict__ plgG,
                             float* __restrict__ wsums,
                             int N) {
    __shared__ __align__(16) float plg[RPAD];   // 5120 B single copy
    {
        const float4* src = (const float4*)plgG;
        float4* dst = (float4*)plg;
        for (int i = threadIdx.x; i < RPAD / 4; i += 256) dst[i] = src[i];
    }
    __syncthreads();

    const int lane = threadIdx.x & 63;
    const int wv   = threadIdx.x >> 6;
    const int wid  = blockIdx.x * 4 + wv;
    const int nw   = gridDim.x * 4;        // multiple of 4 -> k wave-invariant

    float acc = 0.0f;
    int n = wid;
    if (n < N) {
        const int k = (-n) & 3;            // row base % 4 == n % 4 (1205%4==1)

        // ---- hoist the lane's 21 loop-invariant table values to registers
        const float lgp = plg[lane];       // prefix entry (lanes < k use it)
        float4 lgr[5];
        #pragma unroll
        for (int i = 0; i < 5; ++i) {
            const int u = k + 256 * i + 4 * lane;
            lgr[i].x = plg[u];     lgr[i].y = plg[u + 1];
            lgr[i].z = plg[u + 2]; lgr[i].w = plg[u + 3];
        }

        // scalar-only pipeline: labels/weights one row ahead
        int   labc = labels[n];
        float wc   = lweights[n];

        for (;;) {
            const int  n2    = n + nw;
            const bool have2 = (n2 < N);
            int labn = 0; float wn = 0.0f;
            if (have2) { labn = labels[n2]; wn = lweights[n2]; }

            const float* row = cls + (size_t)n * ROW_LEN;
            const float labv = row[labc];
            const float c0   = row[C_CLS];
            const float c1   = row[C_CLS + 1];

            // ---- row load: prefix + 5 float4 segments (segs 0-3 pure classes)
            const float4* vp = (const float4*)(row + k);
            float4 q[5];
            #pragma unroll
            for (int i = 0; i < 4; ++i) q[i] = vp[(size_t)i * 64 + lane];
            {
                int b4 = k + 1024 + 4 * lane;
                float4 t = make_float4(NEG_HUGE, NEG_HUGE, NEG_HUGE, NEG_HUGE);
                if (b4 + 3 <= C_CLS - 1) {
                    t = vp[(size_t)256 + lane];
                } else {
                    if (b4     <= C_CLS - 1) t.x = row[b4];
                    if (b4 + 1 <= C_CLS - 1) t.y = row[b4 + 1];
                    if (b4 + 2 <= C_CLS - 1) t.z = row[b4 + 2];
                }
                q[4] = t;
            }
            float pv = (lane < k) ? row[lane] : NEG_HUGE;

            // ---- pass 1: log2 domain in place, s = sum 2^(xl - 16)
            pv *= LOG2E;
            float s = EXP2(pv - M2FIX);
            #pragma unroll
            for (int i = 0; i < 5; ++i) {
                q[i].x *= LOG2E; q[i].y *= LOG2E;
                q[i].z *= LOG2E; q[i].w *= LOG2E;
                s += EXP2(q[i].x - M2FIX) + EXP2(q[i].y - M2FIX)
                   + EXP2(q[i].z - M2FIX) + EXP2(q[i].w - M2FIX);
            }
            #pragma unroll
            for (int o = 32; o > 0; o >>= 1) s += __shfl_xor(s, o, 64);

            const float L2    = M2FIX + LOG2F_(s);
            const float labv2 = labv * LOG2E;
            const float G     = fmaxf(labv2, L2 + LOG_EPS2);  // L2 + logsm2
            const float W     = L2 + Q_POW * (L2 - G);        // >= max adj
            const float plogl = plg[labc];   // wave-uniform -> LDS broadcast
            const float Wp    = W + plogl;
            const float mW    = -W;

            // ---- pass 2: T = sum 2^(adj - W); label term subtracted after
            // t = min(lg - Wp, -W) == min(lg - plogl, 0) - W
            float T;
            {
                float t = fminf(lgp - Wp, mW);
                float h = fmaxf(pv - G, 0.0f);
                T = EXP2(fmaf(Q_POW, h, pv) + t);
            }
            #pragma unroll
            for (int i = 0; i < 5; ++i) {
                { float t = fminf(lgr[i].x - Wp, mW), h = fmaxf(q[i].x - G, 0.f);
                  T += EXP2(fmaf(Q_POW, h, q[i].x) + t); }
                { float t = fminf(lgr[i].y - Wp, mW), h = fmaxf(q[i].y - G, 0.f);
                  T += EXP2(fmaf(Q_POW, h, q[i].y) + t); }
                { float t = fminf(lgr[i].z - Wp, mW), h = fmaxf(q[i].z - G, 0.f);
                  T += EXP2(fmaf(Q_POW, h, q[i].z) + t); }
                { float t = fminf(lgr[i].w - Wp, mW), h = fmaxf(q[i].w - G, 0.f);
                  T += EXP2(fmaf(Q_POW, h, q[i].w) + t); }
            }
            #pragma unroll
            for (int o = 32; o > 0; o >>= 1) T += __shfl_xor(T, o, 64);
            T -= EXP2(labv2 - W);     // adj[label] == csc[label] exactly
            T = fmaxf(T, 1e-37f);

            // ---- per-row tail (wave-uniform)
            const float nl2 = W + LOG2F_(T);
            const float xx  = (nl2 - labv2) * LN2;
            const float rl  = (xx > 0.0f) ? (xx + log1pf(__expf(-xx)))
                                          : log1pf(__expf(xx));
            const float mm   = fmaxf(c0, c1);
            const float lseb = mm + __logf(__expf(c0 - mm) + __expf(c1 - mm));
            const float ce   = lseb - ((labc == C_CLS) ? c1 : c0);
            const float rlw  = (wc == 1.0f) ? rl : 0.0f;   // pos_mask == 1.0
            acc += rlw + ce * wc;

            if (!have2) break;
            n = n2; labc = labn; wc = wn;
        }
    }

    if (lane == 0) wsums[wid] = acc;   // per-wave partial, plain store
}

// ---------------- dispatch 3: deterministic final sum ----------------
__launch_bounds__(512)
__global__ void reduce_k(const float* __restrict__ wsums, int nb,
                         const int* __restrict__ avg_raw,
                         float* __restrict__ out) {
    int tid = threadIdx.x;
    float s = 0.0f;
    int nb4 = nb >> 2;
    const float4* bp = (const float4*)wsums;
    for (int i = tid; i < nb4; i += 512) {
        float4 v = bp[i];
        s += (v.x + v.y) + (v.z + v.w);
    }
    for (int i = (nb4 << 2) + tid; i < nb; i += 512) s += wsums[i];

    #pragma unroll
    for (int o = 32; o > 0; o >>= 1) s += __shfl_xor(s, o, 64);

    __shared__ float ws8[8];
    int lane = tid & 63, wvi = tid >> 6;
    if (lane == 0) ws8[wvi] = s;
    __syncthreads();
    if (tid == 0) {
        float t = 0.0f;
        #pragma unroll
        for (int i = 0; i < 8; ++i) t += ws8[i];
        int ai = avg_raw[0];
        float af;
        if (ai > 0 && ai < (1 << 26)) {
            af = (float)ai;              // stored as integer
        } else {
            union { int i; float f; } u; // stored as float bits
            u.i = ai;
            af = u.f;
        }
        out[0] = t / af;
    }
}

extern "C" void kernel_launch(void* const* d_in, const int* in_sizes, int n_in,
                              void* d_out, int out_size, void* d_ws, size_t ws_size,
                              hipStream_t stream) {
    const float* cls    = (const float*)d_in[0];
    const int*   labels = (const int*)d_in[1];
    const float* lw     = (const float*)d_in[2];
    const int*   avgp   = (const int*)d_in[3];
    float*       out    = (float*)d_out;

    const int N = in_sizes[1];

    // ws layout: [ float plgG[RPAD] | float wsums[g*4] ]
    float* plgG  = (float*)d_ws;
    float* wsums = (float*)d_ws + RPAD;

    int g = (N + 7) / 8;                 // 4 waves/block * 2 rows/wave
    if (g > 4096) g = 4096;
    if (g < 1) g = 1;

    prep_k<<<1, 1024, 0, stream>>>(labels, N, plgG);
    seesaw_row_k<<<g, 256, 0, stream>>>(cls, labels, lw, plgG, wsums, N);
    reduce_k<<<1, 512, 0, stream>>>(wsums, g * 4, avgp, out);
}

// Round 14
// 48.709 us; speedup vs baseline: 1.1480x; 1.0213x over previous
//
#include <hip/hip_runtime.h>

// SeesawLoss forward, N=32768 rows, C=1203 classes (+2 binary logits).
// Round 14 = RESTORE of round-10, the best measured variant (48.3 us).
// Register-hoisted P*log2(cum) table (loop-invariant per lane), 5 KB LDS
// single-copy table, uncapped VGPR (no min-waves clause -> no spill),
// scalar-only label/weight pipeline, fixed 2^-16 softmax shift (no max
// pass), analytic W bound (no 2nd max pass), label exclusion by
// subtraction, 3 dispatches, deterministic reduction (no float atomics).
//
// Session ledger (dur_us): R1 67.7 -> R2 64.1 -> R3 61.2 -> R4 137 (ordered
// atomics) -> R5 48.6 -> R6 169 (spill) -> R7 86.2 (spill) -> R8 50.9 ->
// R9 60.4 -> R10 48.3 (BEST) -> R11 55.9 -> R12 52.2 -> R13 49.7.
// Structural bound: warm-L3 streaming of the 158 MB input at ~4.2 TB/s
// effective (~38 us) + ~9 us fixed (prep + reduce + graph gaps); compute
// (~10 us chip-wide) hides under it. Occupancy/prefetch/ILP/grid-shape
// all measured insensitive or negative.

#define C_CLS   1203
#define ROW_LEN 1205
#define NBINS   1204
#define RPAD    1280
#define NEG_HUGE (-3.402823466e38f)
#define LOG2E    1.4426950408889634f
#define LN2      0.6931471805599453f
#define LOG_EPS2 (-6.643856189774724f)   // log2(0.01)
#define P_POW    0.8f
#define Q_POW    2.0f
#define M2FIX    16.0f                   // fixed softmax shift (|logits| << 11)

#if __has_builtin(__builtin_amdgcn_exp2f)
#define EXP2(x) __builtin_amdgcn_exp2f(x)
#else
#define EXP2(x) exp2f(x)
#endif
#if __has_builtin(__builtin_amdgcn_logf)
#define LOG2F_(x) __builtin_amdgcn_logf(x)
#else
#define LOG2F_(x) __log2f(x)
#endif

// ---------------- dispatch 1: histogram + single-copy P*log2(count) table ----
__launch_bounds__(1024)
__global__ void prep_k(const int* __restrict__ labels, int N,
                       float* __restrict__ plgG) {
    __shared__ unsigned hist[NBINS];
    for (int i = threadIdx.x; i < NBINS; i += 1024) hist[i] = 0u;
    __syncthreads();

    const int nv = N >> 2;
    const int4* lp = (const int4*)labels;
    for (int i = threadIdx.x; i < nv; i += 1024) {
        int4 v = lp[i];
        atomicAdd(&hist[v.x], 1u); atomicAdd(&hist[v.y], 1u);
        atomicAdd(&hist[v.z], 1u); atomicAdd(&hist[v.w], 1u);
    }
    for (int i = (N & ~3) + (int)threadIdx.x; i < N; i += 1024)
        atomicAdd(&hist[labels[i]], 1u);
    __syncthreads();

    for (int u = threadIdx.x; u < RPAD; u += 1024) {
        float v = 0.0f;
        if (u < NBINS) v = P_POW * LOG2F_(fmaxf((float)hist[u], 1.0f));
        plgG[u] = v;     // pad region = 0 (masked elements are -inf in q)
    }
}

// ---------------- dispatch 2: per-row loss, one wave per row ----------------
__launch_bounds__(256)   // no min-waves clause: let VGPRs float, forbid spill
__global__ void seesaw_row_k(const float* __restrict__ cls,
                             const int* __restrict__ labels,
                             const float* __restrict__ lweights,
                             const float* __restrict__ plgG,
                             float* __restrict__ wsums,
                             int N) {
    __shared__ __align__(16) float plg[RPAD];   // 5120 B single copy
    {
        const float4* src = (const float4*)plgG;
        float4* dst = (float4*)plg;
        for (int i = threadIdx.x; i < RPAD / 4; i += 256) dst[i] = src[i];
    }
    __syncthreads();

    const int lane = threadIdx.x & 63;
    const int wv   = threadIdx.x >> 6;
    const int wid  = blockIdx.x * 4 + wv;
    const int nw   = gridDim.x * 4;        // multiple of 4 -> k wave-invariant

    float acc = 0.0f;
    int n = wid;
    if (n < N) {
        const int k = (-n) & 3;            // row base % 4 == n % 4 (1205%4==1)

        // ---- hoist the lane's 21 loop-invariant table values to registers
        const float lgp = plg[lane];       // prefix entry (lanes < k use it)
        float4 lgr[5];
        #pragma unroll
        for (int i = 0; i < 5; ++i) {
            const int u = k + 256 * i + 4 * lane;
            lgr[i].x = plg[u];     lgr[i].y = plg[u + 1];
            lgr[i].z = plg[u + 2]; lgr[i].w = plg[u + 3];
        }

        // scalar-only pipeline: labels/weights one row ahead
        int   labc = labels[n];
        float wc   = lweights[n];

        for (;;) {
            const int  n2    = n + nw;
            const bool have2 = (n2 < N);
            int labn = 0; float wn = 0.0f;
            if (have2) { labn = labels[n2]; wn = lweights[n2]; }

            const float* row = cls + (size_t)n * ROW_LEN;
            const float labv = row[labc];
            const float c0   = row[C_CLS];
            const float c1   = row[C_CLS + 1];

            // ---- row load: prefix + 5 float4 segments (segs 0-3 pure classes)
            const float4* vp = (const float4*)(row + k);
            float4 q[5];
            #pragma unroll
            for (int i = 0; i < 4; ++i) q[i] = vp[(size_t)i * 64 + lane];
            {
                int b4 = k + 1024 + 4 * lane;
                float4 t = make_float4(NEG_HUGE, NEG_HUGE, NEG_HUGE, NEG_HUGE);
                if (b4 + 3 <= C_CLS - 1) {
                    t = vp[(size_t)256 + lane];
                } else {
                    if (b4     <= C_CLS - 1) t.x = row[b4];
                    if (b4 + 1 <= C_CLS - 1) t.y = row[b4 + 1];
                    if (b4 + 2 <= C_CLS - 1) t.z = row[b4 + 2];
                }
                q[4] = t;
            }
            float pv = (lane < k) ? row[lane] : NEG_HUGE;

            // ---- pass 1: log2 domain in place, s = sum 2^(xl - 16)
            pv *= LOG2E;
            float s = EXP2(pv - M2FIX);
            #pragma unroll
            for (int i = 0; i < 5; ++i) {
                q[i].x *= LOG2E; q[i].y *= LOG2E;
                q[i].z *= LOG2E; q[i].w *= LOG2E;
                s += EXP2(q[i].x - M2FIX) + EXP2(q[i].y - M2FIX)
                   + EXP2(q[i].z - M2FIX) + EXP2(q[i].w - M2FIX);
            }
            #pragma unroll
            for (int o = 32; o > 0; o >>= 1) s += __shfl_xor(s, o, 64);

            const float L2    = M2FIX + LOG2F_(s);
            const float labv2 = labv * LOG2E;
            const float G     = fmaxf(labv2, L2 + LOG_EPS2);  // L2 + logsm2
            const float W     = L2 + Q_POW * (L2 - G);        // >= max adj
            const float plogl = plg[labc];   // wave-uniform -> LDS broadcast
            const float Wp    = W + plogl;
            const float mW    = -W;

            // ---- pass 2: T = sum 2^(adj - W); label term subtracted after
            // t = min(lg - Wp, -W) == min(lg - plogl, 0) - W
            float T;
            {
                float t = fminf(lgp - Wp, mW);
                float h = fmaxf(pv - G, 0.0f);
                T = EXP2(fmaf(Q_POW, h, pv) + t);
            }
            #pragma unroll
            for (int i = 0; i < 5; ++i) {
                { float t = fminf(lgr[i].x - Wp, mW), h = fmaxf(q[i].x - G, 0.f);
                  T += EXP2(fmaf(Q_POW, h, q[i].x) + t); }
                { float t = fminf(lgr[i].y - Wp, mW), h = fmaxf(q[i].y - G, 0.f);
                  T += EXP2(fmaf(Q_POW, h, q[i].y) + t); }
                { float t = fminf(lgr[i].z - Wp, mW), h = fmaxf(q[i].z - G, 0.f);
                  T += EXP2(fmaf(Q_POW, h, q[i].z) + t); }
                { float t = fminf(lgr[i].w - Wp, mW), h = fmaxf(q[i].w - G, 0.f);
                  T += EXP2(fmaf(Q_POW, h, q[i].w) + t); }
            }
            #pragma unroll
            for (int o = 32; o > 0; o >>= 1) T += __shfl_xor(T, o, 64);
            T -= EXP2(labv2 - W);     // adj[label] == csc[label] exactly
            T = fmaxf(T, 1e-37f);

            // ---- per-row tail (wave-uniform)
            const float nl2 = W + LOG2F_(T);
            const float xx  = (nl2 - labv2) * LN2;
            const float rl  = (xx > 0.0f) ? (xx + log1pf(__expf(-xx)))
                                          : log1pf(__expf(xx));
            const float mm   = fmaxf(c0, c1);
            const float lseb = mm + __logf(__expf(c0 - mm) + __expf(c1 - mm));
            const float ce   = lseb - ((labc == C_CLS) ? c1 : c0);
            const float rlw  = (wc == 1.0f) ? rl : 0.0f;   // pos_mask == 1.0
            acc += rlw + ce * wc;

            if (!have2) break;
            n = n2; labc = labn; wc = wn;
        }
    }

    if (lane == 0) wsums[wid] = acc;   // per-wave partial, plain store
}

// ---------------- dispatch 3: deterministic final sum ----------------
__launch_bounds__(512)
__global__ void reduce_k(const float* __restrict__ wsums, int nb,
                         const int* __restrict__ avg_raw,
                         float* __restrict__ out) {
    int tid = threadIdx.x;
    float s = 0.0f;
    int nb4 = nb >> 2;
    const float4* bp = (const float4*)wsums;
    for (int i = tid; i < nb4; i += 512) {
        float4 v = bp[i];
        s += (v.x + v.y) + (v.z + v.w);
    }
    for (int i = (nb4 << 2) + tid; i < nb; i += 512) s += wsums[i];

    #pragma unroll
    for (int o = 32; o > 0; o >>= 1) s += __shfl_xor(s, o, 64);

    __shared__ float ws8[8];
    int lane = tid & 63, wvi = tid >> 6;
    if (lane == 0) ws8[wvi] = s;
    __syncthreads();
    if (tid == 0) {
        float t = 0.0f;
        #pragma unroll
        for (int i = 0; i < 8; ++i) t += ws8[i];
        int ai = avg_raw[0];
        float af;
        if (ai > 0 && ai < (1 << 26)) {
            af = (float)ai;              // stored as integer
        } else {
            union { int i; float f; } u; // stored as float bits
            u.i = ai;
            af = u.f;
        }
        out[0] = t / af;
    }
}

extern "C" void kernel_launch(void* const* d_in, const int* in_sizes, int n_in,
                              void* d_out, int out_size, void* d_ws, size_t ws_size,
                              hipStream_t stream) {
    const float* cls    = (const float*)d_in[0];
    const int*   labels = (const int*)d_in[1];
    const float* lw     = (const float*)d_in[2];
    const int*   avgp   = (const int*)d_in[3];
    float*       out    = (float*)d_out;

    const int N = in_sizes[1];

    // ws layout: [ float plgG[RPAD] | float wsums[g*4] ]
    float* plgG  = (float*)d_ws;
    float* wsums = (float*)d_ws + RPAD;

    int g = (N + 15) / 16;               // 4 waves/block * 4 rows/wave
    if (g > 2048) g = 2048;
    if (g < 1) g = 1;

    prep_k<<<1, 1024, 0, stream>>>(labels, N, plgG);
    seesaw_row_k<<<g, 256, 0, stream>>>(cls, labels, lw, plgG, wsums, N);
    reduce_k<<<1, 512, 0, stream>>>(wsums, g * 4, avgp, out);
}